// Round 19
// baseline (293.776 us; speedup 1.0000x reference)
//
#include <hip/hip_runtime.h>

typedef __attribute__((ext_vector_type(8))) short bf16x8;
typedef __attribute__((ext_vector_type(8))) unsigned short ushort8;
typedef __attribute__((ext_vector_type(4))) float f32x4;

#define NN 50000
#define HH 128

static __device__ __forceinline__ unsigned short f2bf(float f) {
  unsigned u = __builtin_bit_cast(unsigned, f);
  u = u + 0x7FFFu + ((u >> 16) & 1u);
  return (unsigned short)(u >> 16);
}

static __device__ __forceinline__ float bf2f(unsigned short b) {
  return __builtin_bit_cast(float, ((unsigned)b) << 16);
}

static __device__ __forceinline__ bf16x8 bfrag(const unsigned short* __restrict__ w,
                                               int kt, int nt, int lane) {
  return *reinterpret_cast<const bf16x8*>(w + (((kt * 8 + nt) * 64 + lane) << 3));
}

struct SwzJobs {
  const float* src[12];
  unsigned short* dst[12];
};

// ---- prep kernel: cvt_x ∪ weight-swizzle ∪ hist3(+rank record), fused by block range ----
struct PrepParams {
  const float* x; unsigned short* xb; int total8; int cvtBlocks;
  SwzJobs swz; int swzBlocks;
  const int *eiL, *eiM, *eiG; int El, Em, Eg; int* cnt; int* rk;
};
__global__ __launch_bounds__(256) void prep_kernel(PrepParams p) {
  const int t = threadIdx.x;
  int b = blockIdx.x;
  if (b < p.cvtBlocks) {
    int i = b * 256 + t;
    if (i >= p.total8) return;
    const float4* pp = reinterpret_cast<const float4*>(p.x + (long)i * 8);
    float4 f0 = pp[0], f1 = pp[1];
    ushort8 u;
    u[0] = f2bf(f0.x); u[1] = f2bf(f0.y); u[2] = f2bf(f0.z); u[3] = f2bf(f0.w);
    u[4] = f2bf(f1.x); u[5] = f2bf(f1.y); u[6] = f2bf(f1.z); u[7] = f2bf(f1.w);
    *reinterpret_cast<ushort8*>(p.xb + (long)i * 8) = u;
    return;
  }
  b -= p.cvtBlocks;
  if (b < p.swzBlocks) {
    int job, blk;
    if (b < 640) { job = b >> 6; blk = b & 63; }
    else { b -= 640; job = 10 + (b >> 8); blk = b & 255; }
    int o = blk * 256 + t;
    int j = o & 7, lane = (o >> 3) & 63, nt = (o >> 9) & 7, kt = o >> 12;
    int row = kt * 32 + (lane >> 4) * 8 + j;
    int col = nt * 16 + (lane & 15);
    p.swz.dst[job][o] = f2bf(p.swz.src[job][row * 128 + col]);
    return;
  }
  b -= p.swzBlocks;
  const int eg = b * 256 + t;
  int e = eg;
  const int* ei; int E, off;
  if (e < p.El) { ei = p.eiL; E = p.El; off = 0; }
  else if (e < p.El + p.Em) { e -= p.El; ei = p.eiM; E = p.Em; off = NN; }
  else { e -= p.El + p.Em; if (e >= p.Eg) return; ei = p.eiG; E = p.Eg; off = 2 * NN; }
  int old = atomicAdd(p.cnt + off + ei[E + e], 1);
  p.rk[eg] = old;
}

// ---- scan kernels (two-level); final exclusive scan lands in rowptr ----
__global__ void scanA_kernel(const int* __restrict__ cnt, int* __restrict__ offs,
                             int* __restrict__ bsum, int n) {
  const int t = threadIdx.x, lane = t & 63, w = t >> 6;
  const int i = blockIdx.x * 1024 + t;
  __shared__ int wsum[16], wpre[16];
  int v = (i < n) ? cnt[i] : 0;
  int inc = v;
#pragma unroll
  for (int d = 1; d < 64; d <<= 1) {
    int o = __shfl_up(inc, d, 64);
    if (lane >= d) inc += o;
  }
  if (lane == 63) wsum[w] = inc;
  __syncthreads();
  if (t == 0) {
    int run = 0;
#pragma unroll
    for (int k = 0; k < 16; ++k) { wpre[k] = run; run += wsum[k]; }
    wsum[0] = run;
  }
  __syncthreads();
  if (i < n) offs[i] = wpre[w] + inc - v;
  if (t == 0) bsum[blockIdx.x] = wsum[0];
}

__global__ void scanB_kernel(int* __restrict__ bsum, int n) {
  const int t = threadIdx.x, lane = t & 63, w = t >> 6;
  __shared__ int wsum[4];
  int v = (t < n) ? bsum[t] : 0;
  int inc = v;
#pragma unroll
  for (int d = 1; d < 64; d <<= 1) {
    int o = __shfl_up(inc, d, 64);
    if (lane >= d) inc += o;
  }
  if (lane == 63) wsum[w] = inc;
  __syncthreads();
  int wo = 0;
  for (int k = 0; k < w; ++k) wo += wsum[k];
  if (t < n) bsum[t] = wo + inc - v;
}

__global__ void scanC_kernel(const int* __restrict__ offs, int* __restrict__ rowptr,
                             const int* __restrict__ bsum, int n) {
  int i = blockIdx.x * 1024 + threadIdx.x;
  if (i < n) rowptr[i] = offs[i] + bsum[blockIdx.x];
}

// ---- fused scatter ∪ pq kernel (scatter atomic-free: pos = rowptr[d] + rk[e]) ----
struct PQJobs {
  const unsigned short* Wswz[6];
  const float* bias[6];
  unsigned short* out[6];
};
struct SpqParams {
  const int *eiL, *eiM, *eiG;
  const float *eaL, *eaM, *eaG;
  int El, Em, Eg;
  const int* rowptr; const int* rk; unsigned long long* sed; int scatterBlocks;
  const unsigned short* xb; PQJobs pq;
};
__global__ __launch_bounds__(256) void spq_kernel(SpqParams p) {
  const int t = threadIdx.x;
  if (blockIdx.x < p.scatterBlocks) {
    const int eg = blockIdx.x * 256 + t;
    int e = eg;
    const int* ei; const float* ea; int E, off;
    if (e < p.El) { ei = p.eiL; ea = p.eaL; E = p.El; off = 0; }
    else if (e < p.El + p.Em) { e -= p.El; ei = p.eiM; ea = p.eaM; E = p.Em; off = NN; }
    else { e -= p.El + p.Em; if (e >= p.Eg) return; ei = p.eiG; ea = p.eaG; E = p.Eg; off = 2 * NN; }
    int d = ei[E + e];
    int pos = p.rowptr[off + d] + p.rk[eg];
    unsigned long long r =
        (unsigned long long)(unsigned short)ei[e] |
        ((unsigned long long)f2bf(ea[(long)e * 3 + 0]) << 16) |
        ((unsigned long long)f2bf(ea[(long)e * 3 + 1]) << 32) |
        ((unsigned long long)f2bf(ea[(long)e * 3 + 2]) << 48);
    __builtin_nontemporal_store(r, p.sed + pos);
    return;
  }
  const int bid = blockIdx.x - p.scatterBlocks;
  const int jb = bid % 6;
  const int n0 = (bid / 6) * 64;
  const int wave = t >> 6, lane = t & 63;
  const int lr = lane & 15, lgp = lane >> 4;
  const int arow = n0 + wave * 16 + lr;
  const bool aok = arow < NN;
  const unsigned short* W = p.pq.Wswz[jb];
  f32x4 acc[8];
#pragma unroll
  for (int nt = 0; nt < 8; ++nt) acc[nt] = (f32x4){0.f, 0.f, 0.f, 0.f};
#pragma unroll
  for (int kt = 0; kt < 4; ++kt) {
    bf16x8 a = (bf16x8){0, 0, 0, 0, 0, 0, 0, 0};
    if (aok)
      a = *reinterpret_cast<const bf16x8*>(p.xb + (long)arow * HH + kt * 32 + lgp * 8);
#pragma unroll
    for (int nt = 0; nt < 8; ++nt)
      acc[nt] = __builtin_amdgcn_mfma_f32_16x16x32_bf16(
          a, bfrag(W, kt, nt, lane), acc[nt], 0, 0, 0);
  }
  const float* bi = p.pq.bias[jb];
  unsigned short* O = p.pq.out[jb];
#pragma unroll
  for (int nt = 0; nt < 8; ++nt) {
    int col = nt * 16 + lr;
    float bv = bi ? bi[col] : 0.f;
#pragma unroll
    for (int r = 0; r < 4; ++r) {
      int row = n0 + wave * 16 + lgp * 4 + r;
      if (row < NN) O[(long)row * HH + col] = f2bf(acc[nt][r] + bv);
    }
  }
}

// ---- edge kernel: one WAVE per dst (CSR run), 8B packed records (u64) ----
struct EScale2 { const unsigned short *P, *Q; const float* Wc; unsigned short* hag; };
struct EParams2 {
  EScale2 s[3];
  const unsigned long long* sed;
  const int* rowptr; const int* cnt;
};
__global__ __launch_bounds__(256) void edge_kernel(EParams2 prm) {
  const int t = threadIdx.x;
  const int wave = t >> 6, lane = t & 63;
  int gidv = blockIdx.x * 4 + wave;
  if (gidv >= 3 * NN) return;
  const int gid = __builtin_amdgcn_readfirstlane(gidv);
  const int si = (gid >= NN) + (gid >= 2 * NN);
  const int dst = gid - si * NN;
  const EScale2 S = prm.s[si];
  const int base = __builtin_amdgcn_readfirstlane(prm.rowptr[gid]);
  const int len = __builtin_amdgcn_readfirstlane(prm.cnt[gid]);
  const int c2 = lane * 2;

  const float wcA0 = S.Wc[c2],       wcB0 = S.Wc[c2 + 1];
  const float wcA1 = S.Wc[128 + c2], wcB1 = S.Wc[129 + c2];
  const float wcA2 = S.Wc[256 + c2], wcB2 = S.Wc[257 + c2];

  float aA0 = 0.f, aB0 = 0.f, aA1 = 0.f, aB1 = 0.f;
  if (len > 0) {
    ushort2 qv = *reinterpret_cast<const ushort2*>(S.Q + (long)dst * HH + c2);
    const float qA = bf2f(qv.x), qB = bf2f(qv.y);
    const unsigned long long* __restrict__ ep = prm.sed + base;
    int i = 0;
    for (; i + 4 <= len; i += 4) {
      unsigned long long m0 = __builtin_nontemporal_load(ep + i);
      unsigned long long m1 = __builtin_nontemporal_load(ep + i + 1);
      unsigned long long m2 = __builtin_nontemporal_load(ep + i + 2);
      unsigned long long m3 = __builtin_nontemporal_load(ep + i + 3);
      ushort2 p0 = *reinterpret_cast<const ushort2*>(S.P + (long)(unsigned short)m0 * HH + c2);
      ushort2 p1 = *reinterpret_cast<const ushort2*>(S.P + (long)(unsigned short)m1 * HH + c2);
      ushort2 p2 = *reinterpret_cast<const ushort2*>(S.P + (long)(unsigned short)m2 * HH + c2);
      ushort2 p3 = *reinterpret_cast<const ushort2*>(S.P + (long)(unsigned short)m3 * HH + c2);
      float e0x = bf2f((unsigned short)(m0 >> 16)), e0y = bf2f((unsigned short)(m0 >> 32)), e0z = bf2f((unsigned short)(m0 >> 48));
      float e1x = bf2f((unsigned short)(m1 >> 16)), e1y = bf2f((unsigned short)(m1 >> 32)), e1z = bf2f((unsigned short)(m1 >> 48));
      float e2x = bf2f((unsigned short)(m2 >> 16)), e2y = bf2f((unsigned short)(m2 >> 32)), e2z = bf2f((unsigned short)(m2 >> 48));
      float e3x = bf2f((unsigned short)(m3 >> 16)), e3y = bf2f((unsigned short)(m3 >> 32)), e3z = bf2f((unsigned short)(m3 >> 48));
      aA0 += fmaxf(bf2f(p0.x) + qA + e0x * wcA0 + e0y * wcA1 + e0z * wcA2, 0.f);
      aB0 += fmaxf(bf2f(p0.y) + qB + e0x * wcB0 + e0y * wcB1 + e0z * wcB2, 0.f);
      aA1 += fmaxf(bf2f(p1.x) + qA + e1x * wcA0 + e1y * wcA1 + e1z * wcA2, 0.f);
      aB1 += fmaxf(bf2f(p1.y) + qB + e1x * wcB0 + e1y * wcB1 + e1z * wcB2, 0.f);
      aA0 += fmaxf(bf2f(p2.x) + qA + e2x * wcA0 + e2y * wcA1 + e2z * wcA2, 0.f);
      aB0 += fmaxf(bf2f(p2.y) + qB + e2x * wcB0 + e2y * wcB1 + e2z * wcB2, 0.f);
      aA1 += fmaxf(bf2f(p3.x) + qA + e3x * wcA0 + e3y * wcA1 + e3z * wcA2, 0.f);
      aB1 += fmaxf(bf2f(p3.y) + qB + e3x * wcB0 + e3y * wcB1 + e3z * wcB2, 0.f);
    }
    for (; i < len; ++i) {
      unsigned long long m0 = __builtin_nontemporal_load(ep + i);
      ushort2 p0 = *reinterpret_cast<const ushort2*>(S.P + (long)(unsigned short)m0 * HH + c2);
      float e0x = bf2f((unsigned short)(m0 >> 16)), e0y = bf2f((unsigned short)(m0 >> 32)), e0z = bf2f((unsigned short)(m0 >> 48));
      aA0 += fmaxf(bf2f(p0.x) + qA + e0x * wcA0 + e0y * wcA1 + e0z * wcA2, 0.f);
      aB0 += fmaxf(bf2f(p0.y) + qB + e0x * wcB0 + e0y * wcB1 + e0z * wcB2, 0.f);
    }
  }
  *reinterpret_cast<ushort2*>(S.hag + (long)dst * HH + c2) =
      make_ushort2(f2bf(aA0 + aA1), f2bf(aB0 + aB1));
}

// ---- msg kernel: M_s = bf16(hagg_s @ W2_s + deg_s*b2_s) ----
struct MsgScale {
  const unsigned short* H; const unsigned short* W2s; const float* b2; const int* deg;
  unsigned short* M;
};
struct MsgParams { MsgScale s[3]; };
__global__ __launch_bounds__(256) void msg_kernel(MsgParams prm) {
  const int bid = blockIdx.x;
  const int si = bid % 3;
  const int n0 = (bid / 3) * 64;
  const MsgScale S = prm.s[si];
  const int t = threadIdx.x;
  const int wave = t >> 6, lane = t & 63;
  const int lr = lane & 15, lgp = lane >> 4;
  const int arow = n0 + wave * 16 + lr;
  const bool aok = arow < NN;
  f32x4 acc[8];
#pragma unroll
  for (int nt = 0; nt < 8; ++nt) acc[nt] = (f32x4){0.f, 0.f, 0.f, 0.f};
#pragma unroll
  for (int kt = 0; kt < 4; ++kt) {
    bf16x8 a = (bf16x8){0, 0, 0, 0, 0, 0, 0, 0};
    if (aok)
      a = *reinterpret_cast<const bf16x8*>(S.H + (long)arow * HH + kt * 32 + lgp * 8);
#pragma unroll
    for (int nt = 0; nt < 8; ++nt)
      acc[nt] = __builtin_amdgcn_mfma_f32_16x16x32_bf16(
          a, bfrag(S.W2s, kt, nt, lane), acc[nt], 0, 0, 0);
  }
#pragma unroll
  for (int nt = 0; nt < 8; ++nt) {
    int col = nt * 16 + lr;
    float bv = S.b2[col];
#pragma unroll
    for (int r = 0; r < 4; ++r) {
      int row = n0 + wave * 16 + lgp * 4 + r;
      if (row < NN) {
        float dg = (float)S.deg[row];
        S.M[(long)row * HH + col] = f2bf(acc[nt][r] + dg * bv);
      }
    }
  }
}

// ---- node kernel: K=512 streaming GEMM with double-buffered LDS B-staging ----
__global__ __launch_bounds__(256) void node_kernel(
    const float* __restrict__ x, const unsigned short* __restrict__ xb,
    const unsigned short* __restrict__ Ml, const unsigned short* __restrict__ Mm,
    const unsigned short* __restrict__ Mg,
    const unsigned short* __restrict__ Wg, const unsigned short* __restrict__ Wu1,
    const unsigned short* __restrict__ Wu2,
    const float* __restrict__ bg, const float* __restrict__ bu1, const float* __restrict__ bu2,
    const float* __restrict__ gamma, const float* __restrict__ beta,
    float* __restrict__ out) {
  __shared__ unsigned short smem[2][8192];
  const int t = threadIdx.x;
  const int n0 = blockIdx.x * 64;
  const int wave = t >> 6, lane = t & 63;
  const int lr = lane & 15, lgp = lane >> 4;
  const int arow = n0 + wave * 16 + lr;
  const bool aok = arow < NN;

  f32x4 accG[8], accH[8];
#pragma unroll
  for (int nt = 0; nt < 8; ++nt) {
    accG[nt] = (f32x4){0.f, 0.f, 0.f, 0.f};
    accH[nt] = (f32x4){0.f, 0.f, 0.f, 0.f};
  }

  {
    ushort8 g0 = *reinterpret_cast<const ushort8*>(Wg + t * 8);
    ushort8 g1 = *reinterpret_cast<const ushort8*>(Wg + 2048 + t * 8);
    ushort8 u0 = *reinterpret_cast<const ushort8*>(Wu1 + t * 8);
    ushort8 u1 = *reinterpret_cast<const ushort8*>(Wu1 + 2048 + t * 8);
    *reinterpret_cast<ushort8*>(&smem[0][t * 8]) = g0;
    *reinterpret_cast<ushort8*>(&smem[0][2048 + t * 8]) = g1;
    *reinterpret_cast<ushort8*>(&smem[0][4096 + t * 8]) = u0;
    *reinterpret_cast<ushort8*>(&smem[0][6144 + t * 8]) = u1;
  }

#pragma unroll
  for (int kt = 0; kt < 16; ++kt) {
    const int cb = kt & 1, nb = cb ^ 1;
    __syncthreads();
    ushort8 ng0, ng1, nu0, nu1;
    if (kt < 15) {
      const unsigned short* gG = Wg + (kt + 1) * 4096;
      const unsigned short* gU = Wu1 + (kt + 1) * 4096;
      ng0 = *reinterpret_cast<const ushort8*>(gG + t * 8);
      ng1 = *reinterpret_cast<const ushort8*>(gG + 2048 + t * 8);
      nu0 = *reinterpret_cast<const ushort8*>(gU + t * 8);
      nu1 = *reinterpret_cast<const ushort8*>(gU + 2048 + t * 8);
    }
    const unsigned short* S = (kt < 4) ? xb : (kt < 8) ? Ml : (kt < 12) ? Mm : Mg;
    int cbase = ((kt & 3) << 5) + (lgp << 3);
    bf16x8 a = (bf16x8){0, 0, 0, 0, 0, 0, 0, 0};
    if (aok) a = *reinterpret_cast<const bf16x8*>(S + (long)arow * HH + cbase);
#pragma unroll
    for (int nt = 0; nt < 8; ++nt) {
      bf16x8 bgf = *reinterpret_cast<const bf16x8*>(&smem[cb][nt * 512 + lane * 8]);
      accG[nt] = __builtin_amdgcn_mfma_f32_16x16x32_bf16(a, bgf, accG[nt], 0, 0, 0);
      bf16x8 buf_ = *reinterpret_cast<const bf16x8*>(&smem[cb][4096 + nt * 512 + lane * 8]);
      accH[nt] = __builtin_amdgcn_mfma_f32_16x16x32_bf16(a, buf_, accH[nt], 0, 0, 0);
    }
    if (kt < 15) {
      *reinterpret_cast<ushort8*>(&smem[nb][t * 8]) = ng0;
      *reinterpret_cast<ushort8*>(&smem[nb][2048 + t * 8]) = ng1;
      *reinterpret_cast<ushort8*>(&smem[nb][4096 + t * 8]) = nu0;
      *reinterpret_cast<ushort8*>(&smem[nb][6144 + t * 8]) = nu1;
    }
  }
  __syncthreads();

  unsigned short (*Hs)[136] = reinterpret_cast<unsigned short(*)[136]>(&smem[0][0]);

#pragma unroll
  for (int nt = 0; nt < 8; ++nt) {
    int col = nt * 16 + lr;
    float bgv = bg[col], bhv = bu1[col];
#pragma unroll
    for (int r = 0; r < 4; ++r) {
      float g = 1.f / (1.f + __expf(-(accG[nt][r] + bgv)));
      accG[nt][r] = g;
      float h = fmaxf(accH[nt][r] + bhv, 0.f);
      Hs[wave * 16 + lgp * 4 + r][col] = f2bf(h);
    }
  }

  f32x4 accU[8];
#pragma unroll
  for (int nt = 0; nt < 8; ++nt) accU[nt] = (f32x4){0.f, 0.f, 0.f, 0.f};
#pragma unroll
  for (int kt = 0; kt < 4; ++kt) {
    bf16x8 a = *reinterpret_cast<const bf16x8*>(&Hs[wave * 16 + lr][kt * 32 + lgp * 8]);
#pragma unroll
    for (int nt = 0; nt < 8; ++nt) {
      accU[nt] = __builtin_amdgcn_mfma_f32_16x16x32_bf16(a, bfrag(Wu2, kt, nt, lane), accU[nt], 0, 0, 0);
    }
  }

#pragma unroll
  for (int nt = 0; nt < 8; ++nt) {
    int col = nt * 16 + lr;
    float b2v = bu2[col];
#pragma unroll
    for (int r = 0; r < 4; ++r) {
      int row = n0 + wave * 16 + lgp * 4 + r;
      float xv = (row < NN) ? x[(long)row * HH + col] : 0.f;
      float u = accU[nt][r] + b2v;
      float g = accG[nt][r];
      accU[nt][r] = g * u + (1.f - g) * xv;
    }
  }

#pragma unroll
  for (int r = 0; r < 4; ++r) {
    int row = n0 + wave * 16 + lgp * 4 + r;
    float s = 0.f;
#pragma unroll
    for (int nt = 0; nt < 8; ++nt) s += accU[nt][r];
    s += __shfl_xor(s, 1, 64);
    s += __shfl_xor(s, 2, 64);
    s += __shfl_xor(s, 4, 64);
    s += __shfl_xor(s, 8, 64);
    float mu = s * (1.f / 128.f);
    float qv = 0.f;
#pragma unroll
    for (int nt = 0; nt < 8; ++nt) {
      float d = accU[nt][r] - mu;
      qv += d * d;
    }
    qv += __shfl_xor(qv, 1, 64);
    qv += __shfl_xor(qv, 2, 64);
    qv += __shfl_xor(qv, 4, 64);
    qv += __shfl_xor(qv, 8, 64);
    float rs = rsqrtf(qv * (1.f / 128.f) + 1e-5f);
    if (row < NN) {
#pragma unroll
      for (int nt = 0; nt < 8; ++nt) {
        int col = nt * 16 + lr;
        out[(long)row * HH + col] = (accU[nt][r] - mu) * rs * gamma[col] + beta[col];
      }
    }
  }
}

extern "C" void kernel_launch(void* const* d_in, const int* in_sizes, int n_in,
                              void* d_out, int out_size, void* d_ws, size_t ws_size,
                              hipStream_t stream) {
  const float* x = (const float*)d_in[0];
  const int* ei_l = (const int*)d_in[1];
  const float* ea_l = (const float*)d_in[2];
  const int* ei_m = (const int*)d_in[3];
  const float* ea_m = (const float*)d_in[4];
  const int* ei_g = (const int*)d_in[5];
  const float* ea_g = (const float*)d_in[6];
  const float* Wa1 = (const float*)d_in[7];
  const float* ba1 = (const float*)d_in[8];
  const float* Wa2 = (const float*)d_in[9];
  const float* ba2 = (const float*)d_in[10];
  const float* Wb1 = (const float*)d_in[11];
  const float* bb1 = (const float*)d_in[12];
  const float* Wb2 = (const float*)d_in[13];
  const float* bb2 = (const float*)d_in[14];
  const float* Wc1 = (const float*)d_in[15];
  const float* bc1 = (const float*)d_in[16];
  const float* Wc2 = (const float*)d_in[17];
  const float* bc2 = (const float*)d_in[18];
  const float* Wg = (const float*)d_in[19];
  const float* bg = (const float*)d_in[20];
  const float* Wu1 = (const float*)d_in[21];
  const float* bu1 = (const float*)d_in[22];
  const float* Wu2 = (const float*)d_in[23];
  const float* bu2 = (const float*)d_in[24];
  const float* gamma = (const float*)d_in[25];
  const float* beta = (const float*)d_in[26];

  const int El = in_sizes[1] / 2;
  const int Em = in_sizes[3] / 2;
  const int Eg = in_sizes[5] / 2;
  const int Etot = El + Em + Eg;

  // Workspace layout (hagg bf16)
  unsigned short* wp = (unsigned short*)d_ws;
  unsigned short* hl = wp; wp += (size_t)NN * HH;
  unsigned short* hm = wp; wp += (size_t)NN * HH;
  unsigned short* hg = wp; wp += (size_t)NN * HH;
  unsigned short* W1a_a = wp; wp += 128 * 128;
  unsigned short* W1b_a = wp; wp += 128 * 128;
  unsigned short* W2_a  = wp; wp += 128 * 128;
  unsigned short* W1a_b = wp; wp += 128 * 128;
  unsigned short* W1b_b = wp; wp += 128 * 128;
  unsigned short* W2_b  = wp; wp += 128 * 128;
  unsigned short* W1a_c = wp; wp += 128 * 128;
  unsigned short* W1b_c = wp; wp += 128 * 128;
  unsigned short* W2_c  = wp; wp += 128 * 128;
  unsigned short* Wu2_s = wp; wp += 128 * 128;
  unsigned short* Wg_s  = wp; wp += 512 * 128;
  unsigned short* Wu1_s = wp; wp += 512 * 128;
  unsigned short* xb  = wp; wp += (size_t)NN * HH;
  unsigned short* P_l = wp; wp += (size_t)NN * HH;
  unsigned short* Q_l = wp; wp += (size_t)NN * HH;
  unsigned short* P_m = wp; wp += (size_t)NN * HH;
  unsigned short* Q_m = wp; wp += (size_t)NN * HH;
  unsigned short* P_g = wp; wp += (size_t)NN * HH;
  unsigned short* Q_g = wp; wp += (size_t)NN * HH;
  unsigned short* M_l = P_l;   // alias (P dead after edge_kernel)
  unsigned short* M_m = P_m;
  unsigned short* M_g = P_g;
  int* ip = (int*)wp;
  int* cnt    = ip; ip += 3 * NN;   // degrees (kept)
  int* offs   = ip; ip += 3 * NN;   // scanA scratch
  int* rowptr = ip; ip += 3 * NN;   // exclusive scan (kept)
  int* bsum   = ip; ip += 256;
  int* rk     = ip; ip += Etot;     // per-edge rank within dst segment
  size_t off16 = ((size_t)((char*)ip - (char*)d_ws) + 15) & ~(size_t)15;
  unsigned long long* sed = (unsigned long long*)((char*)d_ws + off16);  // Etot 8B records

  hipMemsetAsync(cnt, 0, 3 * NN * sizeof(int), stream);

  // prep: cvt_x ∪ swz ∪ hist+rank (one launch)
  PrepParams pp;
  pp.x = x; pp.xb = xb; pp.total8 = NN * HH / 8;
  pp.cvtBlocks = (pp.total8 + 255) / 256;
  pp.swz.src[0] = Wa1;            pp.swz.dst[0] = W1a_a;
  pp.swz.src[1] = Wa1 + 128*128;  pp.swz.dst[1] = W1b_a;
  pp.swz.src[2] = Wa2;            pp.swz.dst[2] = W2_a;
  pp.swz.src[3] = Wb1;            pp.swz.dst[3] = W1a_b;
  pp.swz.src[4] = Wb1 + 128*128;  pp.swz.dst[4] = W1b_b;
  pp.swz.src[5] = Wb2;            pp.swz.dst[5] = W2_b;
  pp.swz.src[6] = Wc1;            pp.swz.dst[6] = W1a_c;
  pp.swz.src[7] = Wc1 + 128*128;  pp.swz.dst[7] = W1b_c;
  pp.swz.src[8] = Wc2;            pp.swz.dst[8] = W2_c;
  pp.swz.src[9] = Wu2;            pp.swz.dst[9] = Wu2_s;
  pp.swz.src[10] = Wg;            pp.swz.dst[10] = Wg_s;
  pp.swz.src[11] = Wu1;           pp.swz.dst[11] = Wu1_s;
  pp.swzBlocks = 640 + 512;
  pp.eiL = ei_l; pp.eiM = ei_m; pp.eiG = ei_g;
  pp.El = El; pp.Em = Em; pp.Eg = Eg; pp.cnt = cnt; pp.rk = rk;
  const int histBlocks = (Etot + 255) / 256;
  prep_kernel<<<pp.cvtBlocks + pp.swzBlocks + histBlocks, 256, 0, stream>>>(pp);

  // scan (exclusive, into rowptr)
  const int n3 = 3 * NN;
  const int nblkA = (n3 + 1023) / 1024;
  scanA_kernel<<<nblkA, 1024, 0, stream>>>(cnt, offs, bsum, n3);
  scanB_kernel<<<1, 256, 0, stream>>>(bsum, nblkA);
  scanC_kernel<<<nblkA, 1024, 0, stream>>>(offs, rowptr, bsum, n3);

  // fused scatter ∪ pq (scatter atomic-free)
  SpqParams sp;
  sp.eiL = ei_l; sp.eiM = ei_m; sp.eiG = ei_g;
  sp.eaL = ea_l; sp.eaM = ea_m; sp.eaG = ea_g;
  sp.El = El; sp.Em = Em; sp.Eg = Eg;
  sp.rowptr = rowptr; sp.rk = rk; sp.sed = sed;
  sp.scatterBlocks = (Etot + 255) / 256;
  sp.xb = xb;
  sp.pq.Wswz[0] = W1a_a; sp.pq.bias[0] = nullptr; sp.pq.out[0] = P_l;
  sp.pq.Wswz[1] = W1b_a; sp.pq.bias[1] = ba1;     sp.pq.out[1] = Q_l;
  sp.pq.Wswz[2] = W1a_b; sp.pq.bias[2] = nullptr; sp.pq.out[2] = P_m;
  sp.pq.Wswz[3] = W1b_b; sp.pq.bias[3] = bb1;     sp.pq.out[3] = Q_m;
  sp.pq.Wswz[4] = W1a_c; sp.pq.bias[4] = nullptr; sp.pq.out[4] = P_g;
  sp.pq.Wswz[5] = W1b_c; sp.pq.bias[5] = bc1;     sp.pq.out[5] = Q_g;
  const int NB = (NN + 63) / 64;
  spq_kernel<<<sp.scatterBlocks + NB * 6, 256, 0, stream>>>(sp);

  // Edge pass: one wave per dst, 8B records, plain bf16 stores
  EParams2 ep;
  ep.s[0] = {P_l, Q_l, Wa1 + 256 * 128, hl};
  ep.s[1] = {P_m, Q_m, Wb1 + 256 * 128, hm};
  ep.s[2] = {P_g, Q_g, Wc1 + 256 * 128, hg};
  ep.sed = sed; ep.rowptr = rowptr; ep.cnt = cnt;
  edge_kernel<<<(3 * NN + 3) / 4, 256, 0, stream>>>(ep);

  // Msg pass: M_s = bf16(hagg_s @ W2_s + deg*b2_s)
  MsgParams mp;
  mp.s[0] = {hl, W2_a, ba2, cnt,          M_l};
  mp.s[1] = {hm, W2_b, bb2, cnt + NN,     M_m};
  mp.s[2] = {hg, W2_c, bc2, cnt + 2 * NN, M_g};
  msg_kernel<<<3 * NB, 256, 0, stream>>>(mp);

  // Node update + LayerNorm (LDS-staged B, double-buffered)
  node_kernel<<<NB, 256, 0, stream>>>(x, xb, M_l, M_m, M_g, Wg_s, Wu1_s, Wu2_s,
                                      bg, bu1, bu2, gamma, beta, (float*)d_out);
}

// Round 20
// 277.323 us; speedup vs baseline: 1.0593x; 1.0593x over previous
//
#include <hip/hip_runtime.h>

typedef __attribute__((ext_vector_type(8))) short bf16x8;
typedef __attribute__((ext_vector_type(8))) unsigned short ushort8;
typedef __attribute__((ext_vector_type(4))) float f32x4;

#define NN 50000
#define HH 128

static __device__ __forceinline__ unsigned short f2bf(float f) {
  unsigned u = __builtin_bit_cast(unsigned, f);
  u = u + 0x7FFFu + ((u >> 16) & 1u);
  return (unsigned short)(u >> 16);
}

static __device__ __forceinline__ float bf2f(unsigned short b) {
  return __builtin_bit_cast(float, ((unsigned)b) << 16);
}

static __device__ __forceinline__ bf16x8 bfrag(const unsigned short* __restrict__ w,
                                               int kt, int nt, int lane) {
  return *reinterpret_cast<const bf16x8*>(w + (((kt * 8 + nt) * 64 + lane) << 3));
}

struct SwzJobs {
  const float* src[12];
  unsigned short* dst[12];
};

// ---- prep kernel: cvt_x ∪ weight-swizzle ∪ hist3(+rank record), fused by block range ----
struct PrepParams {
  const float* x; unsigned short* xb; int total8; int cvtBlocks;
  SwzJobs swz; int swzBlocks;
  const int *eiL, *eiM, *eiG; int El, Em, Eg; int* cnt; int* rk;
};
__global__ __launch_bounds__(256) void prep_kernel(PrepParams p) {
  const int t = threadIdx.x;
  int b = blockIdx.x;
  if (b < p.cvtBlocks) {
    int i = b * 256 + t;
    if (i >= p.total8) return;
    const float4* pp = reinterpret_cast<const float4*>(p.x + (long)i * 8);
    float4 f0 = pp[0], f1 = pp[1];
    ushort8 u;
    u[0] = f2bf(f0.x); u[1] = f2bf(f0.y); u[2] = f2bf(f0.z); u[3] = f2bf(f0.w);
    u[4] = f2bf(f1.x); u[5] = f2bf(f1.y); u[6] = f2bf(f1.z); u[7] = f2bf(f1.w);
    *reinterpret_cast<ushort8*>(p.xb + (long)i * 8) = u;
    return;
  }
  b -= p.cvtBlocks;
  if (b < p.swzBlocks) {
    int job, blk;
    if (b < 640) { job = b >> 6; blk = b & 63; }
    else { b -= 640; job = 10 + (b >> 8); blk = b & 255; }
    int o = blk * 256 + t;
    int j = o & 7, lane = (o >> 3) & 63, nt = (o >> 9) & 7, kt = o >> 12;
    int row = kt * 32 + (lane >> 4) * 8 + j;
    int col = nt * 16 + (lane & 15);
    p.swz.dst[job][o] = f2bf(p.swz.src[job][row * 128 + col]);
    return;
  }
  b -= p.swzBlocks;
  const int eg = b * 256 + t;
  int e = eg;
  const int* ei; int E, off;
  if (e < p.El) { ei = p.eiL; E = p.El; off = 0; }
  else if (e < p.El + p.Em) { e -= p.El; ei = p.eiM; E = p.Em; off = NN; }
  else { e -= p.El + p.Em; if (e >= p.Eg) return; ei = p.eiG; E = p.Eg; off = 2 * NN; }
  int old = atomicAdd(p.cnt + off + ei[E + e], 1);
  p.rk[eg] = old;
}

// ---- scan kernels (two-level); final exclusive scan lands in rowptr ----
__global__ void scanA_kernel(const int* __restrict__ cnt, int* __restrict__ offs,
                             int* __restrict__ bsum, int n) {
  const int t = threadIdx.x, lane = t & 63, w = t >> 6;
  const int i = blockIdx.x * 1024 + t;
  __shared__ int wsum[16], wpre[16];
  int v = (i < n) ? cnt[i] : 0;
  int inc = v;
#pragma unroll
  for (int d = 1; d < 64; d <<= 1) {
    int o = __shfl_up(inc, d, 64);
    if (lane >= d) inc += o;
  }
  if (lane == 63) wsum[w] = inc;
  __syncthreads();
  if (t == 0) {
    int run = 0;
#pragma unroll
    for (int k = 0; k < 16; ++k) { wpre[k] = run; run += wsum[k]; }
    wsum[0] = run;
  }
  __syncthreads();
  if (i < n) offs[i] = wpre[w] + inc - v;
  if (t == 0) bsum[blockIdx.x] = wsum[0];
}

__global__ void scanB_kernel(int* __restrict__ bsum, int n) {
  const int t = threadIdx.x, lane = t & 63, w = t >> 6;
  __shared__ int wsum[4];
  int v = (t < n) ? bsum[t] : 0;
  int inc = v;
#pragma unroll
  for (int d = 1; d < 64; d <<= 1) {
    int o = __shfl_up(inc, d, 64);
    if (lane >= d) inc += o;
  }
  if (lane == 63) wsum[w] = inc;
  __syncthreads();
  int wo = 0;
  for (int k = 0; k < w; ++k) wo += wsum[k];
  if (t < n) bsum[t] = wo + inc - v;
}

__global__ void scanC_kernel(const int* __restrict__ offs, int* __restrict__ rowptr,
                             const int* __restrict__ bsum, int n) {
  int i = blockIdx.x * 1024 + threadIdx.x;
  if (i < n) rowptr[i] = offs[i] + bsum[blockIdx.x];
}

// ---- fused scatter ∪ pq kernel (scatter atomic-free: pos = rowptr[d] + rk[e]) ----
struct PQJobs {
  const unsigned short* Wswz[6];
  const float* bias[6];
  unsigned short* out[6];
};
struct SpqParams {
  const int *eiL, *eiM, *eiG;
  const float *eaL, *eaM, *eaG;
  int El, Em, Eg;
  const int* rowptr; const int* rk; ushort4* sed; int scatterBlocks;
  const unsigned short* xb; PQJobs pq;
};
__global__ __launch_bounds__(256) void spq_kernel(SpqParams p) {
  const int t = threadIdx.x;
  if (blockIdx.x < p.scatterBlocks) {
    const int eg = blockIdx.x * 256 + t;
    int e = eg;
    const int* ei; const float* ea; int E, off;
    if (e < p.El) { ei = p.eiL; ea = p.eaL; E = p.El; off = 0; }
    else if (e < p.El + p.Em) { e -= p.El; ei = p.eiM; ea = p.eaM; E = p.Em; off = NN; }
    else { e -= p.El + p.Em; if (e >= p.Eg) return; ei = p.eiG; ea = p.eaG; E = p.Eg; off = 2 * NN; }
    int d = ei[E + e];
    int pos = p.rowptr[off + d] + p.rk[eg];
    ushort4 r;
    r.x = (unsigned short)ei[e];
    r.y = f2bf(ea[(long)e * 3 + 0]);
    r.z = f2bf(ea[(long)e * 3 + 1]);
    r.w = f2bf(ea[(long)e * 3 + 2]);
    p.sed[pos] = r;
    return;
  }
  const int bid = blockIdx.x - p.scatterBlocks;
  const int jb = bid % 6;
  const int n0 = (bid / 6) * 64;
  const int wave = t >> 6, lane = t & 63;
  const int lr = lane & 15, lgp = lane >> 4;
  const int arow = n0 + wave * 16 + lr;
  const bool aok = arow < NN;
  const unsigned short* W = p.pq.Wswz[jb];
  f32x4 acc[8];
#pragma unroll
  for (int nt = 0; nt < 8; ++nt) acc[nt] = (f32x4){0.f, 0.f, 0.f, 0.f};
#pragma unroll
  for (int kt = 0; kt < 4; ++kt) {
    bf16x8 a = (bf16x8){0, 0, 0, 0, 0, 0, 0, 0};
    if (aok)
      a = *reinterpret_cast<const bf16x8*>(p.xb + (long)arow * HH + kt * 32 + lgp * 8);
#pragma unroll
    for (int nt = 0; nt < 8; ++nt)
      acc[nt] = __builtin_amdgcn_mfma_f32_16x16x32_bf16(
          a, bfrag(W, kt, nt, lane), acc[nt], 0, 0, 0);
  }
  const float* bi = p.pq.bias[jb];
  unsigned short* O = p.pq.out[jb];
#pragma unroll
  for (int nt = 0; nt < 8; ++nt) {
    int col = nt * 16 + lr;
    float bv = bi ? bi[col] : 0.f;
#pragma unroll
    for (int r = 0; r < 4; ++r) {
      int row = n0 + wave * 16 + lgp * 4 + r;
      if (row < NN) O[(long)row * HH + col] = f2bf(acc[nt][r] + bv);
    }
  }
}

// ---- edge kernel: one WAVE per dst (CSR run), 8B packed records ----
struct EScale2 { const unsigned short *P, *Q; const float* Wc; unsigned short* hag; };
struct EParams2 {
  EScale2 s[3];
  const ushort4* sed;
  const int* rowptr; const int* cnt;
};
__global__ __launch_bounds__(256) void edge_kernel(EParams2 prm) {
  const int t = threadIdx.x;
  const int wave = t >> 6, lane = t & 63;
  int gidv = blockIdx.x * 4 + wave;
  if (gidv >= 3 * NN) return;
  const int gid = __builtin_amdgcn_readfirstlane(gidv);
  const int si = (gid >= NN) + (gid >= 2 * NN);
  const int dst = gid - si * NN;
  const EScale2 S = prm.s[si];
  const int base = __builtin_amdgcn_readfirstlane(prm.rowptr[gid]);
  const int len = __builtin_amdgcn_readfirstlane(prm.cnt[gid]);
  const int c2 = lane * 2;

  const float wcA0 = S.Wc[c2],       wcB0 = S.Wc[c2 + 1];
  const float wcA1 = S.Wc[128 + c2], wcB1 = S.Wc[129 + c2];
  const float wcA2 = S.Wc[256 + c2], wcB2 = S.Wc[257 + c2];

  float aA0 = 0.f, aB0 = 0.f, aA1 = 0.f, aB1 = 0.f;
  if (len > 0) {
    ushort2 qv = *reinterpret_cast<const ushort2*>(S.Q + (long)dst * HH + c2);
    const float qA = bf2f(qv.x), qB = bf2f(qv.y);
    const ushort4* __restrict__ ep = prm.sed + base;
    int i = 0;
    for (; i + 4 <= len; i += 4) {
      ushort4 m0 = ep[i], m1 = ep[i + 1], m2 = ep[i + 2], m3 = ep[i + 3];
      ushort2 p0 = *reinterpret_cast<const ushort2*>(S.P + (long)m0.x * HH + c2);
      ushort2 p1 = *reinterpret_cast<const ushort2*>(S.P + (long)m1.x * HH + c2);
      ushort2 p2 = *reinterpret_cast<const ushort2*>(S.P + (long)m2.x * HH + c2);
      ushort2 p3 = *reinterpret_cast<const ushort2*>(S.P + (long)m3.x * HH + c2);
      float e0x = bf2f(m0.y), e0y = bf2f(m0.z), e0z = bf2f(m0.w);
      float e1x = bf2f(m1.y), e1y = bf2f(m1.z), e1z = bf2f(m1.w);
      float e2x = bf2f(m2.y), e2y = bf2f(m2.z), e2z = bf2f(m2.w);
      float e3x = bf2f(m3.y), e3y = bf2f(m3.z), e3z = bf2f(m3.w);
      aA0 += fmaxf(bf2f(p0.x) + qA + e0x * wcA0 + e0y * wcA1 + e0z * wcA2, 0.f);
      aB0 += fmaxf(bf2f(p0.y) + qB + e0x * wcB0 + e0y * wcB1 + e0z * wcB2, 0.f);
      aA1 += fmaxf(bf2f(p1.x) + qA + e1x * wcA0 + e1y * wcA1 + e1z * wcA2, 0.f);
      aB1 += fmaxf(bf2f(p1.y) + qB + e1x * wcB0 + e1y * wcB1 + e1z * wcB2, 0.f);
      aA0 += fmaxf(bf2f(p2.x) + qA + e2x * wcA0 + e2y * wcA1 + e2z * wcA2, 0.f);
      aB0 += fmaxf(bf2f(p2.y) + qB + e2x * wcB0 + e2y * wcB1 + e2z * wcB2, 0.f);
      aA1 += fmaxf(bf2f(p3.x) + qA + e3x * wcA0 + e3y * wcA1 + e3z * wcA2, 0.f);
      aB1 += fmaxf(bf2f(p3.y) + qB + e3x * wcB0 + e3y * wcB1 + e3z * wcB2, 0.f);
    }
    for (; i < len; ++i) {
      ushort4 m0 = ep[i];
      ushort2 p0 = *reinterpret_cast<const ushort2*>(S.P + (long)m0.x * HH + c2);
      float e0x = bf2f(m0.y), e0y = bf2f(m0.z), e0z = bf2f(m0.w);
      aA0 += fmaxf(bf2f(p0.x) + qA + e0x * wcA0 + e0y * wcA1 + e0z * wcA2, 0.f);
      aB0 += fmaxf(bf2f(p0.y) + qB + e0x * wcB0 + e0y * wcB1 + e0z * wcB2, 0.f);
    }
  }
  *reinterpret_cast<ushort2*>(S.hag + (long)dst * HH + c2) =
      make_ushort2(f2bf(aA0 + aA1), f2bf(aB0 + aB1));
}

// ---- msg kernel: M_s = bf16(hagg_s @ W2_s + deg_s*b2_s) ----
struct MsgScale {
  const unsigned short* H; const unsigned short* W2s; const float* b2; const int* deg;
  unsigned short* M;
};
struct MsgParams { MsgScale s[3]; };
__global__ __launch_bounds__(256) void msg_kernel(MsgParams prm) {
  const int bid = blockIdx.x;
  const int si = bid % 3;
  const int n0 = (bid / 3) * 64;
  const MsgScale S = prm.s[si];
  const int t = threadIdx.x;
  const int wave = t >> 6, lane = t & 63;
  const int lr = lane & 15, lgp = lane >> 4;
  const int arow = n0 + wave * 16 + lr;
  const bool aok = arow < NN;
  f32x4 acc[8];
#pragma unroll
  for (int nt = 0; nt < 8; ++nt) acc[nt] = (f32x4){0.f, 0.f, 0.f, 0.f};
#pragma unroll
  for (int kt = 0; kt < 4; ++kt) {
    bf16x8 a = (bf16x8){0, 0, 0, 0, 0, 0, 0, 0};
    if (aok)
      a = *reinterpret_cast<const bf16x8*>(S.H + (long)arow * HH + kt * 32 + lgp * 8);
#pragma unroll
    for (int nt = 0; nt < 8; ++nt)
      acc[nt] = __builtin_amdgcn_mfma_f32_16x16x32_bf16(
          a, bfrag(S.W2s, kt, nt, lane), acc[nt], 0, 0, 0);
  }
#pragma unroll
  for (int nt = 0; nt < 8; ++nt) {
    int col = nt * 16 + lr;
    float bv = S.b2[col];
#pragma unroll
    for (int r = 0; r < 4; ++r) {
      int row = n0 + wave * 16 + lgp * 4 + r;
      if (row < NN) {
        float dg = (float)S.deg[row];
        S.M[(long)row * HH + col] = f2bf(acc[nt][r] + dg * bv);
      }
    }
  }
}

// ---- node kernel: K=512 streaming GEMM with double-buffered LDS B-staging ----
__global__ __launch_bounds__(256) void node_kernel(
    const float* __restrict__ x, const unsigned short* __restrict__ xb,
    const unsigned short* __restrict__ Ml, const unsigned short* __restrict__ Mm,
    const unsigned short* __restrict__ Mg,
    const unsigned short* __restrict__ Wg, const unsigned short* __restrict__ Wu1,
    const unsigned short* __restrict__ Wu2,
    const float* __restrict__ bg, const float* __restrict__ bu1, const float* __restrict__ bu2,
    const float* __restrict__ gamma, const float* __restrict__ beta,
    float* __restrict__ out) {
  __shared__ unsigned short smem[2][8192];
  const int t = threadIdx.x;
  const int n0 = blockIdx.x * 64;
  const int wave = t >> 6, lane = t & 63;
  const int lr = lane & 15, lgp = lane >> 4;
  const int arow = n0 + wave * 16 + lr;
  const bool aok = arow < NN;

  f32x4 accG[8], accH[8];
#pragma unroll
  for (int nt = 0; nt < 8; ++nt) {
    accG[nt] = (f32x4){0.f, 0.f, 0.f, 0.f};
    accH[nt] = (f32x4){0.f, 0.f, 0.f, 0.f};
  }

  {
    ushort8 g0 = *reinterpret_cast<const ushort8*>(Wg + t * 8);
    ushort8 g1 = *reinterpret_cast<const ushort8*>(Wg + 2048 + t * 8);
    ushort8 u0 = *reinterpret_cast<const ushort8*>(Wu1 + t * 8);
    ushort8 u1 = *reinterpret_cast<const ushort8*>(Wu1 + 2048 + t * 8);
    *reinterpret_cast<ushort8*>(&smem[0][t * 8]) = g0;
    *reinterpret_cast<ushort8*>(&smem[0][2048 + t * 8]) = g1;
    *reinterpret_cast<ushort8*>(&smem[0][4096 + t * 8]) = u0;
    *reinterpret_cast<ushort8*>(&smem[0][6144 + t * 8]) = u1;
  }

#pragma unroll
  for (int kt = 0; kt < 16; ++kt) {
    const int cb = kt & 1, nb = cb ^ 1;
    __syncthreads();
    ushort8 ng0, ng1, nu0, nu1;
    if (kt < 15) {
      const unsigned short* gG = Wg + (kt + 1) * 4096;
      const unsigned short* gU = Wu1 + (kt + 1) * 4096;
      ng0 = *reinterpret_cast<const ushort8*>(gG + t * 8);
      ng1 = *reinterpret_cast<const ushort8*>(gG + 2048 + t * 8);
      nu0 = *reinterpret_cast<const ushort8*>(gU + t * 8);
      nu1 = *reinterpret_cast<const ushort8*>(gU + 2048 + t * 8);
    }
    const unsigned short* S = (kt < 4) ? xb : (kt < 8) ? Ml : (kt < 12) ? Mm : Mg;
    int cbase = ((kt & 3) << 5) + (lgp << 3);
    bf16x8 a = (bf16x8){0, 0, 0, 0, 0, 0, 0, 0};
    if (aok) a = *reinterpret_cast<const bf16x8*>(S + (long)arow * HH + cbase);
#pragma unroll
    for (int nt = 0; nt < 8; ++nt) {
      bf16x8 bgf = *reinterpret_cast<const bf16x8*>(&smem[cb][nt * 512 + lane * 8]);
      accG[nt] = __builtin_amdgcn_mfma_f32_16x16x32_bf16(a, bgf, accG[nt], 0, 0, 0);
      bf16x8 buf_ = *reinterpret_cast<const bf16x8*>(&smem[cb][4096 + nt * 512 + lane * 8]);
      accH[nt] = __builtin_amdgcn_mfma_f32_16x16x32_bf16(a, buf_, accH[nt], 0, 0, 0);
    }
    if (kt < 15) {
      *reinterpret_cast<ushort8*>(&smem[nb][t * 8]) = ng0;
      *reinterpret_cast<ushort8*>(&smem[nb][2048 + t * 8]) = ng1;
      *reinterpret_cast<ushort8*>(&smem[nb][4096 + t * 8]) = nu0;
      *reinterpret_cast<ushort8*>(&smem[nb][6144 + t * 8]) = nu1;
    }
  }
  __syncthreads();

  unsigned short (*Hs)[136] = reinterpret_cast<unsigned short(*)[136]>(&smem[0][0]);

#pragma unroll
  for (int nt = 0; nt < 8; ++nt) {
    int col = nt * 16 + lr;
    float bgv = bg[col], bhv = bu1[col];
#pragma unroll
    for (int r = 0; r < 4; ++r) {
      float g = 1.f / (1.f + __expf(-(accG[nt][r] + bgv)));
      accG[nt][r] = g;
      float h = fmaxf(accH[nt][r] + bhv, 0.f);
      Hs[wave * 16 + lgp * 4 + r][col] = f2bf(h);
    }
  }

  f32x4 accU[8];
#pragma unroll
  for (int nt = 0; nt < 8; ++nt) accU[nt] = (f32x4){0.f, 0.f, 0.f, 0.f};
#pragma unroll
  for (int kt = 0; kt < 4; ++kt) {
    bf16x8 a = *reinterpret_cast<const bf16x8*>(&Hs[wave * 16 + lr][kt * 32 + lgp * 8]);
#pragma unroll
    for (int nt = 0; nt < 8; ++nt) {
      accU[nt] = __builtin_amdgcn_mfma_f32_16x16x32_bf16(a, bfrag(Wu2, kt, nt, lane), accU[nt], 0, 0, 0);
    }
  }

#pragma unroll
  for (int nt = 0; nt < 8; ++nt) {
    int col = nt * 16 + lr;
    float b2v = bu2[col];
#pragma unroll
    for (int r = 0; r < 4; ++r) {
      int row = n0 + wave * 16 + lgp * 4 + r;
      float xv = (row < NN) ? x[(long)row * HH + col] : 0.f;
      float u = accU[nt][r] + b2v;
      float g = accG[nt][r];
      accU[nt][r] = g * u + (1.f - g) * xv;
    }
  }

#pragma unroll
  for (int r = 0; r < 4; ++r) {
    int row = n0 + wave * 16 + lgp * 4 + r;
    float s = 0.f;
#pragma unroll
    for (int nt = 0; nt < 8; ++nt) s += accU[nt][r];
    s += __shfl_xor(s, 1, 64);
    s += __shfl_xor(s, 2, 64);
    s += __shfl_xor(s, 4, 64);
    s += __shfl_xor(s, 8, 64);
    float mu = s * (1.f / 128.f);
    float qv = 0.f;
#pragma unroll
    for (int nt = 0; nt < 8; ++nt) {
      float d = accU[nt][r] - mu;
      qv += d * d;
    }
    qv += __shfl_xor(qv, 1, 64);
    qv += __shfl_xor(qv, 2, 64);
    qv += __shfl_xor(qv, 4, 64);
    qv += __shfl_xor(qv, 8, 64);
    float rs = rsqrtf(qv * (1.f / 128.f) + 1e-5f);
    if (row < NN) {
#pragma unroll
      for (int nt = 0; nt < 8; ++nt) {
        int col = nt * 16 + lr;
        out[(long)row * HH + col] = (accU[nt][r] - mu) * rs * gamma[col] + beta[col];
      }
    }
  }
}

extern "C" void kernel_launch(void* const* d_in, const int* in_sizes, int n_in,
                              void* d_out, int out_size, void* d_ws, size_t ws_size,
                              hipStream_t stream) {
  const float* x = (const float*)d_in[0];
  const int* ei_l = (const int*)d_in[1];
  const float* ea_l = (const float*)d_in[2];
  const int* ei_m = (const int*)d_in[3];
  const float* ea_m = (const float*)d_in[4];
  const int* ei_g = (const int*)d_in[5];
  const float* ea_g = (const float*)d_in[6];
  const float* Wa1 = (const float*)d_in[7];
  const float* ba1 = (const float*)d_in[8];
  const float* Wa2 = (const float*)d_in[9];
  const float* ba2 = (const float*)d_in[10];
  const float* Wb1 = (const float*)d_in[11];
  const float* bb1 = (const float*)d_in[12];
  const float* Wb2 = (const float*)d_in[13];
  const float* bb2 = (const float*)d_in[14];
  const float* Wc1 = (const float*)d_in[15];
  const float* bc1 = (const float*)d_in[16];
  const float* Wc2 = (const float*)d_in[17];
  const float* bc2 = (const float*)d_in[18];
  const float* Wg = (const float*)d_in[19];
  const float* bg = (const float*)d_in[20];
  const float* Wu1 = (const float*)d_in[21];
  const float* bu1 = (const float*)d_in[22];
  const float* Wu2 = (const float*)d_in[23];
  const float* bu2 = (const float*)d_in[24];
  const float* gamma = (const float*)d_in[25];
  const float* beta = (const float*)d_in[26];

  const int El = in_sizes[1] / 2;
  const int Em = in_sizes[3] / 2;
  const int Eg = in_sizes[5] / 2;
  const int Etot = El + Em + Eg;

  // Workspace layout (hagg bf16)
  unsigned short* wp = (unsigned short*)d_ws;
  unsigned short* hl = wp; wp += (size_t)NN * HH;
  unsigned short* hm = wp; wp += (size_t)NN * HH;
  unsigned short* hg = wp; wp += (size_t)NN * HH;
  unsigned short* W1a_a = wp; wp += 128 * 128;
  unsigned short* W1b_a = wp; wp += 128 * 128;
  unsigned short* W2_a  = wp; wp += 128 * 128;
  unsigned short* W1a_b = wp; wp += 128 * 128;
  unsigned short* W1b_b = wp; wp += 128 * 128;
  unsigned short* W2_b  = wp; wp += 128 * 128;
  unsigned short* W1a_c = wp; wp += 128 * 128;
  unsigned short* W1b_c = wp; wp += 128 * 128;
  unsigned short* W2_c  = wp; wp += 128 * 128;
  unsigned short* Wu2_s = wp; wp += 128 * 128;
  unsigned short* Wg_s  = wp; wp += 512 * 128;
  unsigned short* Wu1_s = wp; wp += 512 * 128;
  unsigned short* xb  = wp; wp += (size_t)NN * HH;
  unsigned short* P_l = wp; wp += (size_t)NN * HH;
  unsigned short* Q_l = wp; wp += (size_t)NN * HH;
  unsigned short* P_m = wp; wp += (size_t)NN * HH;
  unsigned short* Q_m = wp; wp += (size_t)NN * HH;
  unsigned short* P_g = wp; wp += (size_t)NN * HH;
  unsigned short* Q_g = wp; wp += (size_t)NN * HH;
  unsigned short* M_l = P_l;   // alias (P dead after edge_kernel)
  unsigned short* M_m = P_m;
  unsigned short* M_g = P_g;
  int* ip = (int*)wp;
  int* cnt    = ip; ip += 3 * NN;   // degrees (kept)
  int* offs   = ip; ip += 3 * NN;   // scanA scratch
  int* rowptr = ip; ip += 3 * NN;   // exclusive scan (kept)
  int* bsum   = ip; ip += 256;
  int* rk     = ip; ip += Etot;     // per-edge rank within dst segment
  size_t off16 = ((size_t)((char*)ip - (char*)d_ws) + 15) & ~(size_t)15;
  ushort4* sed = (ushort4*)((char*)d_ws + off16);   // Etot packed 8B records

  hipMemsetAsync(cnt, 0, 3 * NN * sizeof(int), stream);

  // prep: cvt_x ∪ swz ∪ hist+rank (one launch)
  PrepParams pp;
  pp.x = x; pp.xb = xb; pp.total8 = NN * HH / 8;
  pp.cvtBlocks = (pp.total8 + 255) / 256;
  pp.swz.src[0] = Wa1;            pp.swz.dst[0] = W1a_a;
  pp.swz.src[1] = Wa1 + 128*128;  pp.swz.dst[1] = W1b_a;
  pp.swz.src[2] = Wa2;            pp.swz.dst[2] = W2_a;
  pp.swz.src[3] = Wb1;            pp.swz.dst[3] = W1a_b;
  pp.swz.src[4] = Wb1 + 128*128;  pp.swz.dst[4] = W1b_b;
  pp.swz.src[5] = Wb2;            pp.swz.dst[5] = W2_b;
  pp.swz.src[6] = Wc1;            pp.swz.dst[6] = W1a_c;
  pp.swz.src[7] = Wc1 + 128*128;  pp.swz.dst[7] = W1b_c;
  pp.swz.src[8] = Wc2;            pp.swz.dst[8] = W2_c;
  pp.swz.src[9] = Wu2;            pp.swz.dst[9] = Wu2_s;
  pp.swz.src[10] = Wg;            pp.swz.dst[10] = Wg_s;
  pp.swz.src[11] = Wu1;           pp.swz.dst[11] = Wu1_s;
  pp.swzBlocks = 640 + 512;
  pp.eiL = ei_l; pp.eiM = ei_m; pp.eiG = ei_g;
  pp.El = El; pp.Em = Em; pp.Eg = Eg; pp.cnt = cnt; pp.rk = rk;
  const int histBlocks = (Etot + 255) / 256;
  prep_kernel<<<pp.cvtBlocks + pp.swzBlocks + histBlocks, 256, 0, stream>>>(pp);

  // scan (exclusive, into rowptr)
  const int n3 = 3 * NN;
  const int nblkA = (n3 + 1023) / 1024;
  scanA_kernel<<<nblkA, 1024, 0, stream>>>(cnt, offs, bsum, n3);
  scanB_kernel<<<1, 256, 0, stream>>>(bsum, nblkA);
  scanC_kernel<<<nblkA, 1024, 0, stream>>>(offs, rowptr, bsum, n3);

  // fused scatter ∪ pq (scatter atomic-free)
  SpqParams sp;
  sp.eiL = ei_l; sp.eiM = ei_m; sp.eiG = ei_g;
  sp.eaL = ea_l; sp.eaM = ea_m; sp.eaG = ea_g;
  sp.El = El; sp.Em = Em; sp.Eg = Eg;
  sp.rowptr = rowptr; sp.rk = rk; sp.sed = sed;
  sp.scatterBlocks = (Etot + 255) / 256;
  sp.xb = xb;
  sp.pq.Wswz[0] = W1a_a; sp.pq.bias[0] = nullptr; sp.pq.out[0] = P_l;
  sp.pq.Wswz[1] = W1b_a; sp.pq.bias[1] = ba1;     sp.pq.out[1] = Q_l;
  sp.pq.Wswz[2] = W1a_b; sp.pq.bias[2] = nullptr; sp.pq.out[2] = P_m;
  sp.pq.Wswz[3] = W1b_b; sp.pq.bias[3] = bb1;     sp.pq.out[3] = Q_m;
  sp.pq.Wswz[4] = W1a_c; sp.pq.bias[4] = nullptr; sp.pq.out[4] = P_g;
  sp.pq.Wswz[5] = W1b_c; sp.pq.bias[5] = bc1;     sp.pq.out[5] = Q_g;
  const int NB = (NN + 63) / 64;
  spq_kernel<<<sp.scatterBlocks + NB * 6, 256, 0, stream>>>(sp);

  // Edge pass: one wave per dst, 8B records, plain bf16 stores
  EParams2 ep;
  ep.s[0] = {P_l, Q_l, Wa1 + 256 * 128, hl};
  ep.s[1] = {P_m, Q_m, Wb1 + 256 * 128, hm};
  ep.s[2] = {P_g, Q_g, Wc1 + 256 * 128, hg};
  ep.sed = sed; ep.rowptr = rowptr; ep.cnt = cnt;
  edge_kernel<<<(3 * NN + 3) / 4, 256, 0, stream>>>(ep);

  // Msg pass: M_s = bf16(hagg_s @ W2_s + deg*b2_s)
  MsgParams mp;
  mp.s[0] = {hl, W2_a, ba2, cnt,          M_l};
  mp.s[1] = {hm, W2_b, bb2, cnt + NN,     M_m};
  mp.s[2] = {hg, W2_c, bc2, cnt + 2 * NN, M_g};
  msg_kernel<<<3 * NB, 256, 0, stream>>>(mp);

  // Node update + LayerNorm (LDS-staged B, double-buffered)
  node_kernel<<<NB, 256, 0, stream>>>(x, xb, M_l, M_m, M_g, Wg_s, Wu1_s, Wu2_s,
                                      bg, bu1, bu2, gamma, beta, (float*)d_out);
}